// Round 1
// 245.990 us; speedup vs baseline: 1.0948x; 1.0948x over previous
//
#include <hip/hip_runtime.h>
#include <cstdint>
#include <cstddef>

// PointerNetwork: B=256, S=512, H=128, CHAR/CLASS=10, OUT=64, WE=32
// R2 design (fused-gate, 2-barrier pipelined k_lstm):
//  - active-step skipping (char_ids==0, ~51-71/512 steps per row)
//  - thread (q=T&3 k-slice, u=T>>2 unit): owns the 4 gate cols of unit u.
//    2-stage quad-DPP all-reduce leaves full gate sums in every lane ->
//    gates fused into dot threads (x4 redundant, bit-identical), no thin
//    phases, no zsum LDS round-trips, 2 barriers/step (was 4).
//  - layer-2 h2-half pre-dotted in phase 1 (software pipeline): W2 slice
//    per thread = 32 k from Wh-block (phase1) + 32 k from Wx-block (phase2).
//  - XW1 table (10x512, l1_b folded) staged in LDS once per block.
//  - fp16 weights pinned in VGPRs via asm barrier (192 regs/thread).

#define SLOTS 192

typedef _Float16 f16x2 __attribute__((ext_vector_type(2)));

__device__ __forceinline__ f16x2 as_h2(unsigned int v) {
    union { unsigned int u; f16x2 h; } x; x.u = v; return x.h;
}

#if __has_builtin(__builtin_amdgcn_fdot2)
__device__ __forceinline__ float fdot2(f16x2 a, f16x2 b, float c) {
    return __builtin_amdgcn_fdot2(a, b, c, false);
}
#else
__device__ __forceinline__ float fdot2(f16x2 a, f16x2 b, float c) {
    return c + (float)a.x * (float)b.x + (float)a.y * (float)b.y;
}
#endif

__device__ __forceinline__ float fast_rcp(float x) {
#if __has_builtin(__builtin_amdgcn_rcpf)
    return __builtin_amdgcn_rcpf(x);
#else
    return 1.f / x;
#endif
}
__device__ __forceinline__ float sigm(float x) {
    x = fminf(fmaxf(x, -30.f), 30.f);
    return fast_rcp(1.f + __expf(-x));
}
__device__ __forceinline__ float tanh_fast(float x) {
    x = fminf(fmaxf(x, -15.f), 15.f);
    float e = __expf(-2.f * x);
    return (1.f - e) * fast_rcp(1.f + e);
}

// xor-butterfly add over quads (q = lane&3) via DPP quad_perm, VALU-only.
// After this, all 4 lanes of the quad hold the quad-wide sum (bit-identical).
__device__ __forceinline__ float dpp_bfly4(float v) {
    union { float f; int i; } a, b;
    a.f = v;
    b.i = __builtin_amdgcn_update_dpp(0, a.i, 0xB1, 0xf, 0xf, true);   // quad_perm xor1
    a.f += b.f;
    b.i = __builtin_amdgcn_update_dpp(0, a.i, 0x4E, 0xf, 0xf, true);   // quad_perm xor2
    a.f += b.f;
    return a.f;
}

// 16 chained dot2 over 4 uint4 (8 f16 pairs... 4 pairs per uint4)
__device__ __forceinline__ float dot_u4(float s, const uint4 h, const uint4 w) {
    s = fdot2(as_h2(h.x), as_h2(w.x), s);
    s = fdot2(as_h2(h.y), as_h2(w.y), s);
    s = fdot2(as_h2(h.z), as_h2(w.z), s);
    s = fdot2(as_h2(h.w), as_h2(w.w), s);
    return s;
}

// ---------------- P0: XW1 table (10 x 512) ----------------
__global__ void k_xw1(const float* __restrict__ emb_char,
                      const float* __restrict__ emb_word,
                      const float* __restrict__ Wwc,
                      const float* __restrict__ bwc,
                      const float* __restrict__ l1_Wx,
                      const float* __restrict__ l1_b,
                      float* __restrict__ XW1) {
    __shared__ float xw[64];
    const int w = blockIdx.x;      // word id 0..9
    const int T = threadIdx.x;     // 0..511
    if (T < 64) {
        float acc = emb_char[T] + bwc[T];   // emb_char row 0 (active steps have char==0)
        for (int m = 0; m < 32; ++m) acc += emb_word[w * 32 + m] * Wwc[m * 64 + T];
        xw[T] = acc;
    }
    __syncthreads();
    float acc = l1_b[T];
    for (int k = 0; k < 64; ++k) acc += xw[k] * l1_Wx[k * 512 + T];
    XW1[w * 512 + T] = acc;
}

// ---------------- P1: pack weights fp16, per-(thread,slice) contiguous -------
// thread t = (q=t&3, u=t>>2); col(j) = u + 128*j (j = gate i/f/g/o)
// W1H[t*16 + j*4 + m]: elems e: k = 32q + 2*(4m+e) -> l1_Wh rows (k, k+1)
// W2H[t*32 + ph*16 + j*4 + m]: ph=0 -> l2_Wh rows (h2-half, phase 1)
//                              ph=1 -> l2_Wx rows (h1n-half, phase 2)
__global__ void k_pack2(const float* __restrict__ l1_Wh,
                        const float* __restrict__ l2_Wx,
                        const float* __restrict__ l2_Wh,
                        uint4* __restrict__ W1H, uint4* __restrict__ W2H) {
    const int gid = blockIdx.x * blockDim.x + threadIdx.x;  // 24576 total
    union { uint4 qv; f16x2 h[4]; } out;
    if (gid < 8192) {
        const int t = gid >> 4, i = gid & 15;
        const int q = t & 3, u = t >> 2;
        const int j = i >> 2, m = i & 3;
        const int col = u + 128 * j;
        for (int e = 0; e < 4; ++e) {
            const int k = 32 * q + 2 * (4 * m + e);
            f16x2 p;
            p.x = (_Float16)l1_Wh[k * 512 + col];
            p.y = (_Float16)l1_Wh[(k + 1) * 512 + col];
            out.h[e] = p;
        }
        W1H[gid] = out.qv;
    } else {
        const int gid2 = gid - 8192;
        const int t = gid2 >> 5, i = gid2 & 31;
        const int q = t & 3, u = t >> 2;
        const int ph = i >> 4, jm = i & 15;
        const int j = jm >> 2, m = jm & 3;
        const int col = u + 128 * j;
        const float* __restrict__ src = ph ? l2_Wx : l2_Wh;
        for (int e = 0; e < 4; ++e) {
            const int k = 32 * q + 2 * (4 * m + e);
            f16x2 p;
            p.x = (_Float16)src[k * 512 + col];
            p.y = (_Float16)src[(k + 1) * 512 + col];
            out.h[e] = p;
        }
        W2H[gid2] = out.qv;
    }
}

// ---------------- main recurrent kernel: 1 block per batch row ---------------
__global__ __launch_bounds__(512, 2) void k_lstm(
    const int* __restrict__ char_ids, const int* __restrict__ word_ids,
    const float* __restrict__ XW1, const uint4* __restrict__ W1H,
    const uint4* __restrict__ W2H, const float* __restrict__ l2_b,
    float* __restrict__ hbuf, unsigned short* __restrict__ idxbuf)
{
    const int b    = blockIdx.x;
    const int T    = threadIdx.x;   // 0..511
    const int lane = T & 63;
    const int wv   = T >> 6;        // 0..7
    const int q    = T & 3;         // k-slice 0..3
    const int u    = T >> 2;        // unit 0..127

    __shared__ int   charL[512];
    __shared__ int   wordL[512];
    __shared__ float XW1L[5120];                       // full XW1 table (10x512)
    __shared__ __align__(16) _Float16 h1f[2][128];     // double-buffered h1
    __shared__ __align__(16) _Float16 h2f[128];
    __shared__ short actT[512];
    __shared__ int   ccnt[8];

    charL[T] = char_ids[b * 512 + T];
    wordL[T] = word_ids[b * 512 + T];
#pragma unroll
    for (int i = 0; i < 10; ++i) XW1L[i * 512 + T] = XW1[i * 512 + T];
    __syncthreads();

    // compact the active-step list (ordered) + write idx map
    const bool act = (charL[T] == 0);
    const unsigned long long bmask = __ballot(act);
    if (lane == 0) ccnt[wv] = (int)__popcll(bmask);
    __syncthreads();
    int base = 0;
    for (int i = 0; i < wv; ++i) base += ccnt[i];
    int tot = base;
    for (int i = wv; i < 8; ++i) tot += ccnt[i];
    if (act) actT[base + (int)__popcll(bmask & ((1ull << lane) - 1ull))] = (short)T;
    {
        int cin = base + (int)__popcll(bmask & ((2ull << lane) - 1ull));
        idxbuf[b * 512 + T] = (unsigned short)(cin < SLOTS - 1 ? cin : SLOTS - 1);
    }
    const int nact = tot;

    // init state
    if (T < 128) {
        h1f[0][T] = (_Float16)0.f;
        h1f[1][T] = (_Float16)0.f;
        h2f[T]    = (_Float16)0.f;
        hbuf[(size_t)b * SLOTS * 128 + T] = 0.f;   // slot 0 = zeros
    }
    float c1 = 0.f, c2 = 0.f;                      // replicated across the quad
    const float l2b0 = l2_b[u];
    const float l2b1 = l2_b[128 + u];
    const float l2b2 = l2_b[256 + u];
    const float l2b3 = l2_b[384 + u];

    // persistent fp16 weight slices in VGPRs (48 x uint4 = 192 VGPRs)
    uint4 w1[16], w2[32];
    {
        const uint4* W1t = W1H + (size_t)T * 16;
        const uint4* W2t = W2H + (size_t)T * 32;
#pragma unroll
        for (int i = 0; i < 16; ++i) w1[i] = W1t[i];
#pragma unroll
        for (int i = 0; i < 32; ++i) w2[i] = W2t[i];
    }
#pragma unroll
    for (int i = 0; i < 16; ++i)
        asm volatile("" : "+v"(w1[i].x), "+v"(w1[i].y), "+v"(w1[i].z), "+v"(w1[i].w));
#pragma unroll
    for (int i = 0; i < 32; ++i)
        asm volatile("" : "+v"(w2[i].x), "+v"(w2[i].y), "+v"(w2[i].z), "+v"(w2[i].w));

    __syncthreads();

    for (int a = 0; a < nact; ++a) {
        const int t   = actT[a];
        const int wid = wordL[t];
        const int cur = a & 1;

        // prefetch x-row entries for this unit's 4 gate cols (LDS)
        const float xwi = XW1L[wid * 512 + u];
        const float xwf = XW1L[wid * 512 + 128 + u];
        const float xwg = XW1L[wid * 512 + 256 + u];
        const float xwo = XW1L[wid * 512 + 384 + u];

        // ---- phase 1: L1 dots (h1 slice) + L1 gates + L2 h2-half partials ----
        const uint4* h1r = (const uint4*)&h1f[cur][0];
        const uint4 a0 = h1r[4 * q + 0];
        const uint4 a1 = h1r[4 * q + 1];
        const uint4 a2 = h1r[4 * q + 2];
        const uint4 a3 = h1r[4 * q + 3];
        const uint4* h2r = (const uint4*)h2f;
        const uint4 g0 = h2r[4 * q + 0];
        const uint4 g1 = h2r[4 * q + 1];
        const uint4 g2 = h2r[4 * q + 2];
        const uint4 g3 = h2r[4 * q + 3];

        float acc[4];
#pragma unroll
        for (int j = 0; j < 4; ++j) {
            float s = dot_u4(0.f, a0, w1[4 * j + 0]);
            s = dot_u4(s, a1, w1[4 * j + 1]);
            s = dot_u4(s, a2, w1[4 * j + 2]);
            s = dot_u4(s, a3, w1[4 * j + 3]);
            acc[j] = s;
        }

        // L1 reduce + gates (all lanes; bit-identical across the quad)
        const float zi = dpp_bfly4(acc[0]) + xwi;
        const float zf = dpp_bfly4(acc[1]) + xwf;
        const float zg = dpp_bfly4(acc[2]) + xwg;
        const float zo = dpp_bfly4(acc[3]) + xwo;
        c1 = sigm(zf) * c1 + sigm(zi) * tanh_fast(zg);
        const float h1n = sigm(zo) * tanh_fast(c1);
        if (q == 0) h1f[cur ^ 1][u] = (_Float16)h1n;

        // L2 h2-half partials (uses h2 from previous step; overlaps gate latency)
        float p[4];
#pragma unroll
        for (int j = 0; j < 4; ++j) {
            float s = dot_u4(0.f, g0, w2[4 * j + 0]);
            s = dot_u4(s, g1, w2[4 * j + 1]);
            s = dot_u4(s, g2, w2[4 * j + 2]);
            s = dot_u4(s, g3, w2[4 * j + 3]);
            p[j] = s;
        }
        __syncthreads();

        // ---- phase 2: L2 h1n-half dots + L2 gates + writes ----
        const uint4* h1nr = (const uint4*)&h1f[cur ^ 1][0];
        const uint4 e0 = h1nr[4 * q + 0];
        const uint4 e1 = h1nr[4 * q + 1];
        const uint4 e2 = h1nr[4 * q + 2];
        const uint4 e3 = h1nr[4 * q + 3];
#pragma unroll
        for (int j = 0; j < 4; ++j) {
            float s = p[j];
            s = dot_u4(s, e0, w2[16 + 4 * j + 0]);
            s = dot_u4(s, e1, w2[16 + 4 * j + 1]);
            s = dot_u4(s, e2, w2[16 + 4 * j + 2]);
            s = dot_u4(s, e3, w2[16 + 4 * j + 3]);
            p[j] = s;
        }
        const float y0 = dpp_bfly4(p[0]) + l2b0;
        const float y1 = dpp_bfly4(p[1]) + l2b1;
        const float y2 = dpp_bfly4(p[2]) + l2b2;
        const float y3 = dpp_bfly4(p[3]) + l2b3;
        c2 = sigm(y1) * c2 + sigm(y0) * tanh_fast(y2);
        const float h2v = sigm(y3) * tanh_fast(c2);
        if (q == 0) {
            h2f[u] = (_Float16)h2v;
            const int slot = (a + 1 < SLOTS - 1) ? a + 1 : SLOTS - 1;
            hbuf[((size_t)b * SLOTS + slot) * 128 + u] = h2v;
        }
        __syncthreads();
    }
}

// ---------------- C1: subject gather -> beta/gamma per row -------------------
__global__ void k_subject(const int* __restrict__ subject_ids,
                          const unsigned short* __restrict__ idxbuf,
                          const float* __restrict__ hbuf,
                          const float* __restrict__ beta_W, const float* __restrict__ beta_b,
                          const float* __restrict__ gamma_W, const float* __restrict__ gamma_b,
                          float* __restrict__ betaO, float* __restrict__ gammaO)
{
    const int b = blockIdx.x;
    const int u = threadIdx.x;   // 0..127
    __shared__ float subj[256];
    const int s0 = subject_ids[b * 2 + 0];
    const int s1 = subject_ids[b * 2 + 1];
    const int i0 = idxbuf[b * 512 + s0];
    const int i1 = idxbuf[b * 512 + s1];
    subj[u]       = hbuf[((size_t)b * SLOTS + i0) * 128 + u];
    subj[128 + u] = hbuf[((size_t)b * SLOTS + i1) * 128 + u];
    __syncthreads();
    float ab = beta_b[u], ag = gamma_b[u];
    for (int c = 0; c < 256; ++c) {
        const float s = subj[c];
        ab += s * beta_W[c * 128 + u];
        ag += s * gamma_W[c * 128 + u];
    }
    betaO[b * 128 + u]  = ab;
    gammaO[b * 128 + u] = ag;
}

// ---------------- C2: per-slot LN + po/sub heads, then scatter ---------------
// po(s,o) = rs*sum_c(gm[c]*pw[c][o]*h[s][c]) - u*rs*K2[o] + K1[o]
//   K1[o] = po_b[o] + sum_c bt[c]*pw[c][o];  K2[o] = sum_c gm[c]*pw[c][o]
__global__ __launch_bounds__(256) void k_out2(
    const unsigned short* __restrict__ idxbuf, const float* __restrict__ hbuf,
    const float* __restrict__ betaO, const float* __restrict__ gammaO,
    const float* __restrict__ sub_W, const float* __restrict__ sub_b,
    const float* __restrict__ po_W, const float* __restrict__ po_b,
    float* __restrict__ out)
{
    const int b = blockIdx.x;
    const int T = threadIdx.x;   // 0..255
    __shared__ float A[20][132];          // A[o][c] = gm[c]*po_W[c*20+o]
    __shared__ float K1[20], K2[20];
    __shared__ float gm[128], bt[128];
    __shared__ float urs[192][2];
    __shared__ float povals[192 * 20];
    __shared__ float subv[192 * 2];
    __shared__ unsigned short idxr[512];
    __shared__ float swl[256];

    if (T < 128) { gm[T] = gammaO[b * 128 + T]; bt[T] = betaO[b * 128 + T]; }
    idxr[T] = idxbuf[b * 512 + T];
    idxr[256 + T] = idxbuf[b * 512 + 256 + T];
    swl[T] = sub_W[T];
    __syncthreads();

    // A fill + K1/K2 + per-slot stats & sub head
    for (int i = T; i < 2560; i += 256) {
        const int o = i >> 7, c = i & 127;
        A[o][c] = gm[c] * po_W[c * 20 + o];
    }
    if (T < 20) {
        float k1 = po_b[T], k2 = 0.f;
        for (int c = 0; c < 128; ++c) {
            const float pw = po_W[c * 20 + T];
            k1 += bt[c] * pw;
            k2 += gm[c] * pw;
        }
        K1[T] = k1; K2[T] = k2;
    }
    const int nslot = (int)idxr[511] + 1;
    const float sb0 = sub_b[0], sb1 = sub_b[1];
    for (int s = T; s < nslot; s += 256) {
        const float4* hp4 = (const float4*)(hbuf + ((size_t)b * SLOTS + s) * 128);
        float sum = 0.f, s2 = 0.f, sub0 = sb0, sub1 = sb1;
        for (int c4 = 0; c4 < 32; ++c4) {
            const float4 h = hp4[c4];
            sum += (h.x + h.y) + (h.z + h.w);
            s2  += h.x * h.x + h.y * h.y + h.z * h.z + h.w * h.w;
            const int c = 4 * c4;
            sub0 += h.x * swl[2 * c] + h.y * swl[2 * c + 2] + h.z * swl[2 * c + 4] + h.w * swl[2 * c + 6];
            sub1 += h.x * swl[2 * c + 1] + h.y * swl[2 * c + 3] + h.z * swl[2 * c + 5] + h.w * swl[2 * c + 7];
        }
        const float u = sum * (1.f / 128.f);
        const float v = fmaxf(s2 * (1.f / 128.f) - u * u, 0.f);
        urs[s][0] = u;
        urs[s][1] = 1.f / sqrtf(v + 1e-12f);
        subv[2 * s] = sub0; subv[2 * s + 1] = sub1;
    }
    __syncthreads();

    // po head per (slot, o)
    for (int i = T; i < nslot * 20; i += 256) {
        const int s = i / 20, o = i - 20 * s;
        const float u = urs[s][0], rs = urs[s][1];
        const float4* hp4 = (const float4*)(hbuf + ((size_t)b * SLOTS + s) * 128);
        const float* Ao = &A[o][0];
        float acc = 0.f;
        for (int c4 = 0; c4 < 32; ++c4) {
            const float4 h = hp4[c4];
            const float4 aa = *(const float4*)&Ao[4 * c4];
            acc += h.x * aa.x + h.y * aa.y + h.z * aa.z + h.w * aa.w;
        }
        povals[i] = rs * acc - u * rs * K2[o] + K1[o];
    }
    __syncthreads();

    // scatter
    for (int i = T; i < 2560; i += 256) {
        const int t = i / 5, j = i - 5 * t;
        const int sl = idxr[t];
        const float4 v = *(const float4*)&povals[sl * 20 + 4 * j];
        *(float4*)&out[262144 + ((size_t)(b * 512 + t)) * 20 + 4 * j] = v;
    }
    for (int i = T; i < 512; i += 256) {
        const int sl = idxr[i];
        float2 v; v.x = subv[2 * sl]; v.y = subv[2 * sl + 1];
        *(float2*)&out[((size_t)(b * 512 + i)) * 2] = v;
    }
}

extern "C" void kernel_launch(void* const* d_in, const int* in_sizes, int n_in,
                              void* d_out, int out_size, void* d_ws, size_t ws_size,
                              hipStream_t stream) {
    (void)in_sizes; (void)n_in; (void)out_size; (void)ws_size;
    const int*   char_ids    = (const int*)d_in[0];
    const int*   word_ids    = (const int*)d_in[1];
    const int*   subject_ids = (const int*)d_in[2];
    const float* emb_char    = (const float*)d_in[3];
    const float* emb_word    = (const float*)d_in[4];
    const float* Wwc         = (const float*)d_in[5];
    const float* bwc         = (const float*)d_in[6];
    const float* l1_Wx       = (const float*)d_in[7];
    const float* l1_Wh       = (const float*)d_in[8];
    const float* l1_b        = (const float*)d_in[9];
    const float* l2_Wx       = (const float*)d_in[10];
    const float* l2_Wh       = (const float*)d_in[11];
    const float* l2_b        = (const float*)d_in[12];
    const float* beta_W      = (const float*)d_in[13];
    const float* beta_b      = (const float*)d_in[14];
    const float* gamma_W     = (const float*)d_in[15];
    const float* gamma_b     = (const float*)d_in[16];
    const float* sub_W       = (const float*)d_in[17];
    const float* sub_b       = (const float*)d_in[18];
    const float* po_W        = (const float*)d_in[19];
    const float* po_b        = (const float*)d_in[20];
    float* out = (float*)d_out;

    char* ws = (char*)d_ws;
    float*          XW1    = (float*)(ws + 0);          // 20480 B (pad to 32768)
    uint4*          W1H    = (uint4*)(ws + 32768);      // 131072 B
    uint4*          W2H    = (uint4*)(ws + 163840);     // 262144 B
    float*          betaO  = (float*)(ws + 425984);     // 131072 B
    float*          gammaO = (float*)(ws + 557056);     // 131072 B
    unsigned short* idxbuf = (unsigned short*)(ws + 688128);  // 262144 B
    float*          hbuf   = (float*)(ws + 950272);     // 256*192*128*4 = 25165824 B

    k_xw1<<<dim3(10), dim3(512), 0, stream>>>(emb_char, emb_word, Wwc, bwc, l1_Wx, l1_b, XW1);
    k_pack2<<<dim3(96), dim3(256), 0, stream>>>(l1_Wh, l2_Wx, l2_Wh, W1H, W2H);
    k_lstm<<<dim3(256), dim3(512), 0, stream>>>(char_ids, word_ids, XW1, W1H, W2H,
                                                l2_b, hbuf, idxbuf);
    k_subject<<<dim3(256), dim3(128), 0, stream>>>(subject_ids, idxbuf, hbuf,
                                                   beta_W, beta_b, gamma_W, gamma_b,
                                                   betaO, gammaO);
    k_out2<<<dim3(256), dim3(256), 0, stream>>>(idxbuf, hbuf, betaO, gammaO,
                                                sub_W, sub_b, po_W, po_b, out);
}

// Round 2
// 244.701 us; speedup vs baseline: 1.1006x; 1.0053x over previous
//
#include <hip/hip_runtime.h>
#include <cstdint>
#include <cstddef>

// PointerNetwork: B=256, S=512, H=128, CHAR/CLASS=10, OUT=64, WE=32
// R3 design (1-barrier superphase k_lstm):
//  - active-step skipping (char_ids==0, ~51-71/512 steps per row)
//  - thread (q=T&3 k-slice, u=T>>2 unit): owns the 4 gate cols of unit u.
//    2-stage quad-DPP all-reduce -> gates fused in-lane (x4 redundant,
//    bit-identical across the quad).
//  - superphase pipeline: after the barrier publishing h1n(a), BOTH
//    L2(a) = h1n(a)*W2x + h2(a-1)*W2h  and  L1(a+1) = x(a+1) + h1n(a)*W1h
//    are ready (they share operand h1n(a)). One superphase computes both,
//    ONE barrier per step (was 2), two independent gate chains overlap.
//  - XW1 table (10x512, l1_b folded) staged in LDS once per block.
//  - fp16 weights pinned in VGPRs via asm barrier (192 regs/thread).

#define SLOTS 192

typedef _Float16 f16x2 __attribute__((ext_vector_type(2)));

__device__ __forceinline__ f16x2 as_h2(unsigned int v) {
    union { unsigned int u; f16x2 h; } x; x.u = v; return x.h;
}

#if __has_builtin(__builtin_amdgcn_fdot2)
__device__ __forceinline__ float fdot2(f16x2 a, f16x2 b, float c) {
    return __builtin_amdgcn_fdot2(a, b, c, false);
}
#else
__device__ __forceinline__ float fdot2(f16x2 a, f16x2 b, float c) {
    return c + (float)a.x * (float)b.x + (float)a.y * (float)b.y;
}
#endif

__device__ __forceinline__ float fast_rcp(float x) {
#if __has_builtin(__builtin_amdgcn_rcpf)
    return __builtin_amdgcn_rcpf(x);
#else
    return 1.f / x;
#endif
}
__device__ __forceinline__ float sigm(float x) {
    x = fminf(fmaxf(x, -30.f), 30.f);
    return fast_rcp(1.f + __expf(-x));
}
__device__ __forceinline__ float tanh_fast(float x) {
    x = fminf(fmaxf(x, -15.f), 15.f);
    float e = __expf(-2.f * x);
    return (1.f - e) * fast_rcp(1.f + e);
}

// xor-butterfly add over quads (q = lane&3) via DPP quad_perm, VALU-only.
// After this, all 4 lanes of the quad hold the quad-wide sum (bit-identical:
// both stages are commutative-rounding-identical adds).
__device__ __forceinline__ float dpp_bfly4(float v) {
    union { float f; int i; } a, b;
    a.f = v;
    b.i = __builtin_amdgcn_update_dpp(0, a.i, 0xB1, 0xf, 0xf, true);   // quad_perm xor1
    a.f += b.f;
    b.i = __builtin_amdgcn_update_dpp(0, a.i, 0x4E, 0xf, 0xf, true);   // quad_perm xor2
    a.f += b.f;
    return a.f;
}

__device__ __forceinline__ float dot_u4(float s, const uint4 h, const uint4 w) {
    s = fdot2(as_h2(h.x), as_h2(w.x), s);
    s = fdot2(as_h2(h.y), as_h2(w.y), s);
    s = fdot2(as_h2(h.z), as_h2(w.z), s);
    s = fdot2(as_h2(h.w), as_h2(w.w), s);
    return s;
}

// ---------------- P0: XW1 table (10 x 512) ----------------
__global__ void k_xw1(const float* __restrict__ emb_char,
                      const float* __restrict__ emb_word,
                      const float* __restrict__ Wwc,
                      const float* __restrict__ bwc,
                      const float* __restrict__ l1_Wx,
                      const float* __restrict__ l1_b,
                      float* __restrict__ XW1) {
    __shared__ float xw[64];
    const int w = blockIdx.x;      // word id 0..9
    const int T = threadIdx.x;     // 0..511
    if (T < 64) {
        float acc = emb_char[T] + bwc[T];   // emb_char row 0 (active steps have char==0)
        for (int m = 0; m < 32; ++m) acc += emb_word[w * 32 + m] * Wwc[m * 64 + T];
        xw[T] = acc;
    }
    __syncthreads();
    float acc = l1_b[T];
    for (int k = 0; k < 64; ++k) acc += xw[k] * l1_Wx[k * 512 + T];
    XW1[w * 512 + T] = acc;
}

// ---------------- P1: pack weights fp16, per-(thread,slice) contiguous -------
// thread t = (q=t&3, u=t>>2); col(j) = u + 128*j (j = gate i/f/g/o)
// W1H[t*16 + j*4 + m]: elems e: k = 32q + 2*(4m+e) -> l1_Wh rows (k, k+1)
// W2H[t*32 + ph*16 + j*4 + m]: ph=0 -> l2_Wh rows (h2-half)
//                              ph=1 -> l2_Wx rows (h1n-half)
__global__ void k_pack2(const float* __restrict__ l1_Wh,
                        const float* __restrict__ l2_Wx,
                        const float* __restrict__ l2_Wh,
                        uint4* __restrict__ W1H, uint4* __restrict__ W2H) {
    const int gid = blockIdx.x * blockDim.x + threadIdx.x;  // 24576 total
    union { uint4 qv; f16x2 h[4]; } out;
    if (gid < 8192) {
        const int t = gid >> 4, i = gid & 15;
        const int q = t & 3, u = t >> 2;
        const int j = i >> 2, m = i & 3;
        const int col = u + 128 * j;
        for (int e = 0; e < 4; ++e) {
            const int k = 32 * q + 2 * (4 * m + e);
            f16x2 p;
            p.x = (_Float16)l1_Wh[k * 512 + col];
            p.y = (_Float16)l1_Wh[(k + 1) * 512 + col];
            out.h[e] = p;
        }
        W1H[gid] = out.qv;
    } else {
        const int gid2 = gid - 8192;
        const int t = gid2 >> 5, i = gid2 & 31;
        const int q = t & 3, u = t >> 2;
        const int ph = i >> 4, jm = i & 15;
        const int j = jm >> 2, m = jm & 3;
        const int col = u + 128 * j;
        const float* __restrict__ src = ph ? l2_Wx : l2_Wh;
        for (int e = 0; e < 4; ++e) {
            const int k = 32 * q + 2 * (4 * m + e);
            f16x2 p;
            p.x = (_Float16)src[k * 512 + col];
            p.y = (_Float16)src[(k + 1) * 512 + col];
            out.h[e] = p;
        }
        W2H[gid2] = out.qv;
    }
}

// ---------------- main recurrent kernel: 1 block per batch row ---------------
__global__ __launch_bounds__(512, 2) void k_lstm(
    const int* __restrict__ char_ids, const int* __restrict__ word_ids,
    const float* __restrict__ XW1, const uint4* __restrict__ W1H,
    const uint4* __restrict__ W2H, const float* __restrict__ l2_b,
    float* __restrict__ hbuf, unsigned short* __restrict__ idxbuf)
{
    const int b    = blockIdx.x;
    const int T    = threadIdx.x;   // 0..511
    const int lane = T & 63;
    const int wv   = T >> 6;        // 0..7
    const int q    = T & 3;         // k-slice 0..3
    const int u    = T >> 2;        // unit 0..127

    __shared__ int   charL[512];
    __shared__ int   wordL[512];
    __shared__ float XW1L[5120];                       // full XW1 table (10x512)
    __shared__ __align__(16) _Float16 h1f[2][128];     // double-buffered h1
    __shared__ __align__(16) _Float16 h2f[2][128];     // double-buffered h2
    __shared__ short actT[512];
    __shared__ int   ccnt[8];

    charL[T] = char_ids[b * 512 + T];
    wordL[T] = word_ids[b * 512 + T];
#pragma unroll
    for (int i = 0; i < 10; ++i) XW1L[i * 512 + T] = XW1[i * 512 + T];
    __syncthreads();

    // compact the active-step list (ordered) + write idx map
    const bool act = (charL[T] == 0);
    const unsigned long long bmask = __ballot(act);
    if (lane == 0) ccnt[wv] = (int)__popcll(bmask);
    __syncthreads();
    int base = 0;
    for (int i = 0; i < wv; ++i) base += ccnt[i];
    int tot = base;
    for (int i = wv; i < 8; ++i) tot += ccnt[i];
    if (act) actT[base + (int)__popcll(bmask & ((1ull << lane) - 1ull))] = (short)T;
    {
        int cin = base + (int)__popcll(bmask & ((2ull << lane) - 1ull));
        idxbuf[b * 512 + T] = (unsigned short)(cin < SLOTS - 1 ? cin : SLOTS - 1);
    }
    const int nact = tot;

    // init state
    if (T < 128) {
        h1f[0][T] = (_Float16)0.f;
        h1f[1][T] = (_Float16)0.f;
        h2f[0][T] = (_Float16)0.f;
        h2f[1][T] = (_Float16)0.f;
        hbuf[(size_t)b * SLOTS * 128 + T] = 0.f;   // slot 0 = zeros
    }
    float c1 = 0.f, c2 = 0.f;                      // replicated across the quad
    const float l2b0 = l2_b[u];
    const float l2b1 = l2_b[128 + u];
    const float l2b2 = l2_b[256 + u];
    const float l2b3 = l2_b[384 + u];

    // persistent fp16 weight slices in VGPRs (48 x uint4 = 192 VGPRs)
    uint4 w1[16], w2[32];
    {
        const uint4* W1t = W1H + (size_t)T * 16;
        const uint4* W2t = W2H + (size_t)T * 32;
#pragma unroll
        for (int i = 0; i < 16; ++i) w1[i] = W1t[i];
#pragma unroll
        for (int i = 0; i < 32; ++i) w2[i] = W2t[i];
    }
#pragma unroll
    for (int i = 0; i < 16; ++i)
        asm volatile("" : "+v"(w1[i].x), "+v"(w1[i].y), "+v"(w1[i].z), "+v"(w1[i].w));
#pragma unroll
    for (int i = 0; i < 32; ++i)
        asm volatile("" : "+v"(w2[i].x), "+v"(w2[i].y), "+v"(w2[i].z), "+v"(w2[i].w));

    __syncthreads();

    // prologue: L1 gates for step 0 (h1 == 0 -> Wh dots are zero, z = xw)
    if (nact > 0) {
        const int w0_ = wordL[actT[0]];
        const float zi = XW1L[w0_ * 512 + u];
        const float zg = XW1L[w0_ * 512 + 256 + u];
        const float zo = XW1L[w0_ * 512 + 384 + u];
        c1 = sigm(zi) * tanh_fast(zg);             // c1_old == 0
        const float h1n = sigm(zo) * tanh_fast(c1);
        if (q == 0) h1f[0][u] = (_Float16)h1n;
        __syncthreads();
    }

    // superphase a: reads h1n(a) [H1S], h2(a-1) [H2S];
    //   computes L2(a) -> h2(a) into H2D + hbuf, and L1(a+1) -> h1n(a+1) into H1D.
#define LSTM_STEP(H1S, H2S, H1D, H2D)                                          \
    {                                                                          \
        const uint4* h1r = (const uint4*)&H1S[0] + 4 * q;                      \
        const uint4 a0 = h1r[0], a1 = h1r[1], a2 = h1r[2], a3 = h1r[3];        \
        const uint4* h2r = (const uint4*)&H2S[0] + 4 * q;                      \
        const uint4 g0 = h2r[0], g1 = h2r[1], g2 = h2r[2], g3 = h2r[3];        \
        const bool more = (a + 1 < nact);                                      \
        const int wid = more ? wordL[actT[a + 1]] : 0;                         \
        const float xwi = XW1L[wid * 512 + u];                                 \
        const float xwf = XW1L[wid * 512 + 128 + u];                           \
        const float xwg = XW1L[wid * 512 + 256 + u];                           \
        const float xwo = XW1L[wid * 512 + 384 + u];                           \
        float p[4];                                                            \
        _Pragma("unroll")                                                      \
        for (int j = 0; j < 4; ++j) {                                          \
            float s = dot_u4(0.f, g0, w2[4 * j + 0]);                          \
            s = dot_u4(s, g1, w2[4 * j + 1]);                                  \
            s = dot_u4(s, g2, w2[4 * j + 2]);                                  \
            s = dot_u4(s, g3, w2[4 * j + 3]);                                  \
            s = dot_u4(s, a0, w2[16 + 4 * j + 0]);                             \
            s = dot_u4(s, a1, w2[16 + 4 * j + 1]);                             \
            s = dot_u4(s, a2, w2[16 + 4 * j + 2]);                             \
            s = dot_u4(s, a3, w2[16 + 4 * j + 3]);                             \
            p[j] = s;                                                          \
        }                                                                      \
        const float y0 = dpp_bfly4(p[0]) + l2b0;                               \
        const float y1 = dpp_bfly4(p[1]) + l2b1;                               \
        const float y2 = dpp_bfly4(p[2]) + l2b2;                               \
        const float y3 = dpp_bfly4(p[3]) + l2b3;                               \
        c2 = sigm(y1) * c2 + sigm(y0) * tanh_fast(y2);                         \
        const float h2v = sigm(y3) * tanh_fast(c2);                            \
        if (q == 0) {                                                          \
            H2D[u] = (_Float16)h2v;                                            \
            const int slot = (a + 1 < SLOTS - 1) ? a + 1 : SLOTS - 1;          \
            hbuf[((size_t)b * SLOTS + slot) * 128 + u] = h2v;                  \
        }                                                                      \
        if (more) {                                                            \
            float r0, r1, r2, r3;                                              \
            {                                                                  \
                float r = dot_u4(0.f, a0, w1[0]);                              \
                r = dot_u4(r, a1, w1[1]);                                      \
                r = dot_u4(r, a2, w1[2]);                                      \
                r = dot_u4(r, a3, w1[3]);                                      \
                r0 = r;                                                        \
                r = dot_u4(0.f, a0, w1[4]);                                    \
                r = dot_u4(r, a1, w1[5]);                                      \
                r = dot_u4(r, a2, w1[6]);                                      \
                r = dot_u4(r, a3, w1[7]);                                      \
                r1 = r;                                                        \
                r = dot_u4(0.f, a0, w1[8]);                                    \
                r = dot_u4(r, a1, w1[9]);                                      \
                r = dot_u4(r, a2, w1[10]);                                     \
                r = dot_u4(r, a3, w1[11]);                                     \
                r2 = r;                                                        \
                r = dot_u4(0.f, a0, w1[12]);                                   \
                r = dot_u4(r, a1, w1[13]);                                     \
                r = dot_u4(r, a2, w1[14]);                                     \
                r = dot_u4(r, a3, w1[15]);                                     \
                r3 = r;                                                        \
            }                                                                  \
            const float zi = dpp_bfly4(r0) + xwi;                              \
            const float zf = dpp_bfly4(r1) + xwf;                              \
            const float zg = dpp_bfly4(r2) + xwg;                              \
            const float zo = dpp_bfly4(r3) + xwo;                              \
            c1 = sigm(zf) * c1 + sigm(zi) * tanh_fast(zg);                     \
            const float h1n = sigm(zo) * tanh_fast(c1);                        \
            if (q == 0) H1D[u] = (_Float16)h1n;                                \
        }                                                                      \
        __syncthreads();                                                       \
    }

    int a = 0;
    while (a < nact) {
        LSTM_STEP(h1f[0], h2f[0], h1f[1], h2f[1]);
        ++a;
        if (a >= nact) break;
        LSTM_STEP(h1f[1], h2f[1], h1f[0], h2f[0]);
        ++a;
    }
#undef LSTM_STEP
}

// ---------------- C1: subject gather -> beta/gamma per row -------------------
__global__ __launch_bounds__(256) void k_subject(
    const int* __restrict__ subject_ids,
    const unsigned short* __restrict__ idxbuf,
    const float* __restrict__ hbuf,
    const float* __restrict__ beta_W, const float* __restrict__ beta_b,
    const float* __restrict__ gamma_W, const float* __restrict__ gamma_b,
    float* __restrict__ betaO, float* __restrict__ gammaO)
{
    const int b = blockIdx.x;
    const int T = threadIdx.x;      // 0..255
    const int u = T & 127, half = T >> 7;
    __shared__ float subj[256];
    const int s0 = subject_ids[b * 2 + 0];
    const int s1 = subject_ids[b * 2 + 1];
    const int i0 = idxbuf[b * 512 + s0];
    const int i1 = idxbuf[b * 512 + s1];
    const int slot = half ? i1 : i0;
    subj[T] = hbuf[((size_t)b * SLOTS + slot) * 128 + u];
    __syncthreads();
    const float* __restrict__ W = half ? gamma_W : beta_W;
    float acc = half ? gamma_b[u] : beta_b[u];
    for (int c = 0; c < 256; ++c) acc += subj[c] * W[c * 128 + u];
    if (half) gammaO[b * 128 + u] = acc;
    else      betaO[b * 128 + u]  = acc;
}

// ---------------- C2: per-slot LN + po/sub heads, then scatter ---------------
// po(s,o) = rs*sum_c(gm[c]*pw[c][o]*h[s][c]) - u*rs*K2[o] + K1[o]
//   K1[o] = po_b[o] + sum_c bt[c]*pw[c][o];  K2[o] = sum_c gm[c]*pw[c][o]
__global__ __launch_bounds__(256) void k_out2(
    const unsigned short* __restrict__ idxbuf, const float* __restrict__ hbuf,
    const float* __restrict__ betaO, const float* __restrict__ gammaO,
    const float* __restrict__ sub_W, const float* __restrict__ sub_b,
    const float* __restrict__ po_W, const float* __restrict__ po_b,
    float* __restrict__ out)
{
    const int b = blockIdx.x;
    const int T = threadIdx.x;   // 0..255
    __shared__ float A[20][132];          // A[o][c] = gm[c]*po_W[c*20+o]
    __shared__ float K1[20], K2[20];
    __shared__ float gm[128], bt[128];
    __shared__ float urs[192][2];
    __shared__ float povals[192 * 20];
    __shared__ float subv[192 * 2];
    __shared__ unsigned short idxr[512];
    __shared__ float swl[256];

    if (T < 128) { gm[T] = gammaO[b * 128 + T]; bt[T] = betaO[b * 128 + T]; }
    idxr[T] = idxbuf[b * 512 + T];
    idxr[256 + T] = idxbuf[b * 512 + 256 + T];
    swl[T] = sub_W[T];
    __syncthreads();

    // A fill + K1/K2 + per-slot stats & sub head
    for (int i = T; i < 2560; i += 256) {
        const int o = i >> 7, c = i & 127;
        A[o][c] = gm[c] * po_W[c * 20 + o];
    }
    if (T < 20) {
        float k1 = po_b[T], k2 = 0.f;
        for (int c = 0; c < 128; ++c) {
            const float pw = po_W[c * 20 + T];
            k1 += bt[c] * pw;
            k2 += gm[c] * pw;
        }
        K1[T] = k1; K2[T] = k2;
    }
    const int nslot = (int)idxr[511] + 1;
    const float sb0 = sub_b[0], sb1 = sub_b[1];
    for (int s = T; s < nslot; s += 256) {
        const float4* hp4 = (const float4*)(hbuf + ((size_t)b * SLOTS + s) * 128);
        float sum = 0.f, s2 = 0.f, sub0 = sb0, sub1 = sb1;
        for (int c4 = 0; c4 < 32; ++c4) {
            const float4 h = hp4[c4];
            sum += (h.x + h.y) + (h.z + h.w);
            s2  += h.x * h.x + h.y * h.y + h.z * h.z + h.w * h.w;
            const int c = 4 * c4;
            sub0 += h.x * swl[2 * c] + h.y * swl[2 * c + 2] + h.z * swl[2 * c + 4] + h.w * swl[2 * c + 6];
            sub1 += h.x * swl[2 * c + 1] + h.y * swl[2 * c + 3] + h.z * swl[2 * c + 5] + h.w * swl[2 * c + 7];
        }
        const float u = sum * (1.f / 128.f);
        const float v = fmaxf(s2 * (1.f / 128.f) - u * u, 0.f);
        urs[s][0] = u;
        urs[s][1] = 1.f / sqrtf(v + 1e-12f);
        subv[2 * s] = sub0; subv[2 * s + 1] = sub1;
    }
    __syncthreads();

    // po head per (slot, o)
    for (int i = T; i < nslot * 20; i += 256) {
        const int s = i / 20, o = i - 20 * s;
        const float u = urs[s][0], rs = urs[s][1];
        const float4* hp4 = (const float4*)(hbuf + ((size_t)b * SLOTS + s) * 128);
        const float* Ao = &A[o][0];
        float acc = 0.f;
        for (int c4 = 0; c4 < 32; ++c4) {
            const float4 h = hp4[c4];
            const float4 aa = *(const float4*)&Ao[4 * c4];
            acc += h.x * aa.x + h.y * aa.y + h.z * aa.z + h.w * aa.w;
        }
        povals[i] = rs * acc - u * rs * K2[o] + K1[o];
    }
    __syncthreads();

    // scatter
    for (int i = T; i < 2560; i += 256) {
        const int t = i / 5, j = i - 5 * t;
        const int sl = idxr[t];
        const float4 v = *(const float4*)&povals[sl * 20 + 4 * j];
        *(float4*)&out[262144 + ((size_t)(b * 512 + t)) * 20 + 4 * j] = v;
    }
    for (int i = T; i < 512; i += 256) {
        const int sl = idxr[i];
        float2 v; v.x = subv[2 * sl]; v.y = subv[2 * sl + 1];
        *(float2*)&out[((size_t)(b * 512 + i)) * 2] = v;
    }
}

extern "C" void kernel_launch(void* const* d_in, const int* in_sizes, int n_in,
                              void* d_out, int out_size, void* d_ws, size_t ws_size,
                              hipStream_t stream) {
    (void)in_sizes; (void)n_in; (void)out_size; (void)ws_size;
    const int*   char_ids    = (const int*)d_in[0];
    const int*   word_ids    = (const int*)d_in[1];
    const int*   subject_ids = (const int*)d_in[2];
    const float* emb_char    = (const float*)d_in[3];
    const float* emb_word    = (const float*)d_in[4];
    const float* Wwc         = (const float*)d_in[5];
    const float* bwc         = (const float*)d_in[6];
    const float* l1_Wx       = (const float*)d_in[7];
    const float* l1_Wh       = (const float*)d_in[8];
    const float* l1_b        = (const float*)d_in[9];
    const float* l2_Wx       = (const float*)d_in[10];
    const float* l2_Wh       = (const float*)d_in[11];
    const float* l2_b        = (const float*)d_in[12];
    const float* beta_W      = (const float*)d_in[13];
    const float* beta_b      = (const float*)d_in[14];
    const float* gamma_W     = (const float*)d_in[15];
    const float* gamma_b     = (const float*)d_in[16];
    const float* sub_W       = (const float*)d_in[17];
    const float* sub_b       = (const float*)d_in[18];
    const float* po_W        = (const float*)d_in[19];
    const float* po_b        = (const float*)d_in[20];
    float* out = (float*)d_out;

    char* ws = (char*)d_ws;
    float*          XW1    = (float*)(ws + 0);          // 20480 B (pad to 32768)
    uint4*          W1H    = (uint4*)(ws + 32768);      // 131072 B
    uint4*          W2H    = (uint4*)(ws + 163840);     // 262144 B
    float*          betaO  = (float*)(ws + 425984);     // 131072 B
    float*          gammaO = (float*)(ws + 557056);     // 131072 B
    unsigned short* idxbuf = (unsigned short*)(ws + 688128);  // 262144 B
    float*          hbuf   = (float*)(ws + 950272);     // 256*192*128*4 = 25165824 B

    k_xw1<<<dim3(10), dim3(512), 0, stream>>>(emb_char, emb_word, Wwc, bwc, l1_Wx, l1_b, XW1);
    k_pack2<<<dim3(96), dim3(256), 0, stream>>>(l1_Wh, l2_Wx, l2_Wh, W1H, W2H);
    k_lstm<<<dim3(256), dim3(512), 0, stream>>>(char_ids, word_ids, XW1, W1H, W2H,
                                                l2_b, hbuf, idxbuf);
    k_subject<<<dim3(256), dim3(256), 0, stream>>>(subject_ids, idxbuf, hbuf,
                                                   beta_W, beta_b, gamma_W, gamma_b,
                                                   betaO, gammaO);
    k_out2<<<dim3(256), dim3(256), 0, stream>>>(idxbuf, hbuf, betaO, gammaO,
                                                sub_W, sub_b, po_W, po_b, out);
}